// Round 5
// baseline (199.730 us; speedup 1.0000x reference)
//
#include <hip/hip_runtime.h>
#include <math.h>

#define WIN 11
#define HALF 5
#define SZ 32
#define PST 33          /* padded LDS row stride */
#define BB 4
#define NG 16
#define NP 64
#define IH 640
#define IW 640
#define CPIX 1024       /* 32*32 per channel */
#define NPIX 3072       /* 3*32*32 per crop */
#define NCROP 320       /* 64 gt + 256 pred */
#define NPAIR 4096      /* 4*16*64 */
#define NSLOT 512       /* k_pair y-blocks per channel; grid-stride covers count>NSLOT */
#define SSIM_C1 6.5025f
#define SSIM_C2 58.5225f

// exp(-(i-5)^2/4.5)/sum — 11-tap Gaussian, sigma=1.5, compile-time
#define GW_INIT {0.001028379f, 0.007598757f, 0.036000791f, 0.109360748f, \
                 0.213005174f, 0.266011868f, 0.213005174f, 0.109360748f, \
                 0.036000791f, 0.007598757f, 0.001028379f}

// ---- fused: crop-resize + mu/sigma (blocks 0..959) | validity list (blocks 960..975) ----
__global__ __launch_bounds__(256) void k_crop_valid(const float* __restrict__ imgs,
                                                    const float* __restrict__ gt,
                                                    const float* __restrict__ pr,
                                                    float* __restrict__ crops,
                                                    float* __restrict__ mus,
                                                    float* __restrict__ sigs,
                                                    int* __restrict__ list,
                                                    int* __restrict__ count) {
    const int blk = blockIdx.x;
    const int t = threadIdx.x;

    if (blk >= 3 * NCROP) {
        // ---- validity -> compact list (16 blocks x 256 = 4096 pairs) ----
        int idx = (blk - 3 * NCROP) * 256 + t;
        int b = idx >> 10;
        int r = idx & 1023;
        int gi = r >> 6, pi = r & 63;
        const float* g = gt + (b * NG + gi) * 4;
        const float* p = pr + (b * NP + pi) * 4;
        float gx = g[0], gy = g[1], gw = g[2], gh = g[3];
        float px = p[0], py = p[1], pw = p[2], ph = p[3];
        float tlx = fmaxf(gx - gw * 0.5f, px - pw * 0.5f);
        float tly = fmaxf(gy - gh * 0.5f, py - ph * 0.5f);
        float brx = fminf(gx + gw * 0.5f, px + pw * 0.5f);
        float bry = fminf(gy + gh * 0.5f, py + ph * 0.5f);
        float en = ((tlx < brx) && (tly < bry)) ? 1.f : 0.f;
        float ai = (brx - tlx) * (bry - tly) * en;
        float iou = ai / (gw * gh + pw * ph - ai + 1e-16f);
        if (iou > 0.3f && pw > 2.f && ph > 2.f) {
            int s = atomicAdd(count, 1);   // wave-coalesced (G12)
            list[s] = idx;
        }
        return;
    }

    // ---- crop path ----
    const int crop = blk / 3;
    const int c = blk - crop * 3;
    int b;
    const float* box;
    if (crop < BB * NG) {
        b = crop >> 4;
        box = gt + crop * 4;
    } else {
        int id = crop - BB * NG;
        b = id >> 6;
        box = pr + id * 4;
    }

    __shared__ float s_fx[SZ], s_fy[SZ];
    __shared__ int s_ix0[SZ], s_ix1[SZ], s_iy0[SZ], s_iy1[SZ];
    __shared__ float cr[SZ][PST];
    __shared__ float t1[SZ][PST];
    __shared__ float t2[SZ][PST];

    if (t < SZ) {
        float cx = box[0], cy = box[1], bw = box[2], bh = box[3];
        float x0 = fminf(fmaxf(floorf(cx - bw * 0.5f), 0.f), (float)(IW - 1));
        float x1 = fminf(fmaxf(floorf(cx + bw * 0.5f), 0.f), (float)IW);
        float y0 = fminf(fmaxf(floorf(cy - bh * 0.5f), 0.f), (float)(IH - 1));
        float y1 = fminf(fmaxf(floorf(cy + bh * 0.5f), 0.f), (float)IH);
        float wp = fmaxf(x1 - x0, 1.f);
        float hp = fmaxf(y1 - y0, 1.f);
        float d = (float)t + 0.5f;
        float sx = x0 + fminf(fmaxf(d * wp * (1.f / 32.f) - 0.5f, 0.f), wp - 1.f);
        float flx = floorf(sx);
        s_ix0[t] = (int)flx;
        s_fx[t] = sx - flx;
        s_ix1[t] = min((int)flx + 1, (int)(x0 + wp - 1.f));
        float sy = y0 + fminf(fmaxf(d * hp * (1.f / 32.f) - 0.5f, 0.f), hp - 1.f);
        float fly = floorf(sy);
        s_iy0[t] = (int)fly;
        s_fy[t] = sy - fly;
        s_iy1[t] = min((int)fly + 1, (int)(y0 + hp - 1.f));
    }
    __syncthreads();

    const float* ic = imgs + ((size_t)b * 3 + c) * IH * IW;
    const int y = t >> 3;          // thread owns pixels 4t..4t+3 (same row)
    const int xb = (t & 7) * 4;
    const float fy = s_fy[y];
    const float* r0 = ic + s_iy0[y] * IW;
    const float* r1 = ic + s_iy1[y] * IW;
    float vv[4];
#pragma unroll
    for (int j = 0; j < 4; ++j) {
        int x = xb + j;
        int ix0 = s_ix0[x], ix1 = s_ix1[x];
        float fx = s_fx[x];
        float v00 = r0[ix0], v01 = r0[ix1], v10 = r1[ix0], v11 = r1[ix1];
        float v = v00 * (1.f - fy) * (1.f - fx) + v01 * (1.f - fy) * fx +
                  v10 * fy * (1.f - fx) + v11 * fy * fx;
        vv[j] = v;
        cr[y][x] = v;
    }
    float* dst = crops + (size_t)crop * NPIX + c * CPIX + t * 4;
    *(float4*)dst = make_float4(vv[0], vv[1], vv[2], vv[3]);
    __syncthreads();

    constexpr float GW[WIN] = GW_INIT;
    // horizontal pass on x and x^2
#pragma unroll
    for (int j = 0; j < 4; ++j) {
        int x = xb + j;
        float a1 = 0.f, a2 = 0.f;
#pragma unroll
        for (int k = 0; k < WIN; ++k) {
            int xx = x + k - HALF;
            if (xx >= 0 && xx < SZ) {
                float v = cr[y][xx];
                a1 += GW[k] * v;
                a2 += GW[k] * v * v;
            }
        }
        t1[y][x] = a1;
        t2[y][x] = a2;
    }
    __syncthreads();
    // vertical pass
    float m[4], s[4];
#pragma unroll
    for (int j = 0; j < 4; ++j) {
        int x = xb + j;
        float a1 = 0.f, a2 = 0.f;
#pragma unroll
        for (int k = 0; k < WIN; ++k) {
            int yy = y + k - HALF;
            if (yy >= 0 && yy < SZ) {
                a1 += GW[k] * t1[yy][x];
                a2 += GW[k] * t2[yy][x];
            }
        }
        m[j] = a1;
        s[j] = a2 - a1 * a1;
    }
    float* mdst = mus + (size_t)crop * NPIX + c * CPIX + t * 4;
    float* sdst = sigs + (size_t)crop * NPIX + c * CPIX + t * 4;
    *(float4*)mdst = make_float4(m[0], m[1], m[2], m[3]);
    *(float4*)sdst = make_float4(s[0], s[1], s[2], s[3]);
}

// ---- per-(valid-pair, channel) SSIM + L1 via compact list; fused last-block final reduce ----
__global__ __launch_bounds__(256) void k_pair(const int* __restrict__ list,
                                              const int* __restrict__ count,
                                              const float* __restrict__ crops,
                                              const float* __restrict__ mus,
                                              const float* __restrict__ sigs,
                                              float* __restrict__ pairL1,
                                              float* __restrict__ pairSS,
                                              int* __restrict__ done,
                                              float* __restrict__ out) {
    const int c = blockIdx.x;      // 0..2
    const int n = *count;
    const int t = threadIdx.x;
    const int y = t >> 3;
    const int xb = (t & 7) * 4;
    const int wave = t >> 6, lane = t & 63;

    __shared__ float gp[SZ][PST];
    __shared__ float tmp[SZ][PST];
    __shared__ float rl[4], rs[4];
    __shared__ bool s_last;
    constexpr float GW[WIN] = GW_INIT;

    for (int slot = blockIdx.y; slot < n; slot += NSLOT) {
        const int pair = list[slot];
        const int b = pair >> 10;
        const int r = pair & 1023;
        const int gi = r >> 6, pi = r & 63;
        const size_t goff = (size_t)(b * NG + gi) * NPIX + c * CPIX;
        const size_t poff = (size_t)(BB * NG + b * NP + pi) * NPIX + c * CPIX;

        float4 gv = *(const float4*)(crops + goff + t * 4);
        float4 pv = *(const float4*)(crops + poff + t * 4);
        // hoist mu/sigma loads: in flight across both conv phases
        float4 mg = *(const float4*)(mus + goff + t * 4);
        float4 mp = *(const float4*)(mus + poff + t * 4);
        float4 sg = *(const float4*)(sigs + goff + t * 4);
        float4 sp = *(const float4*)(sigs + poff + t * 4);

        float l1 = fabsf(gv.x - pv.x) + fabsf(gv.y - pv.y) +
                   fabsf(gv.z - pv.z) + fabsf(gv.w - pv.w);
        gp[y][xb + 0] = gv.x * pv.x;
        gp[y][xb + 1] = gv.y * pv.y;
        gp[y][xb + 2] = gv.z * pv.z;
        gp[y][xb + 3] = gv.w * pv.w;
        __syncthreads();

#pragma unroll
        for (int j = 0; j < 4; ++j) {
            int x = xb + j;
            float a = 0.f;
#pragma unroll
            for (int k = 0; k < WIN; ++k) {
                int xx = x + k - HALF;
                if (xx >= 0 && xx < SZ) a += GW[k] * gp[y][xx];
            }
            tmp[y][x] = a;
        }
        __syncthreads();

        float mgv[4] = {mg.x, mg.y, mg.z, mg.w};
        float mpv[4] = {mp.x, mp.y, mp.z, mp.w};
        float sgv[4] = {sg.x, sg.y, sg.z, sg.w};
        float spv[4] = {sp.x, sp.y, sp.z, sp.w};
        float ss = 0.f;
#pragma unroll
        for (int j = 0; j < 4; ++j) {
            int x = xb + j;
            float a = 0.f;
#pragma unroll
            for (int k = 0; k < WIN; ++k) {
                int yy = y + k - HALF;
                if (yy >= 0 && yy < SZ) a += GW[k] * tmp[yy][x];
            }
            float m1 = mgv[j], m2 = mpv[j];
            float sgp = a - m1 * m2;
            float num = (2.f * m1 * m2 + SSIM_C1) * (2.f * sgp + SSIM_C2);
            float den = (m1 * m1 + m2 * m2 + SSIM_C1) * (sgv[j] + spv[j] + SSIM_C2);
            ss += num / den;
        }

        // block reduction: 64-lane shuffle, then LDS across 4 waves
#pragma unroll
        for (int off = 32; off > 0; off >>= 1) {
            l1 += __shfl_down(l1, off);
            ss += __shfl_down(ss, off);
        }
        if (lane == 0) { rl[wave] = l1; rs[wave] = ss; }
        __syncthreads();
        if (t == 0) {
            pairL1[slot * 3 + c] = rl[0] + rl[1] + rl[2] + rl[3];
            pairSS[slot * 3 + c] = rs[0] + rs[1] + rs[2] + rs[3];
        }
    }

    // ---- last-block final reduce (replaces separate k_final launch) ----
    __threadfence();   // release our pairL1/pairSS writes
    __syncthreads();
    if (t == 0) {
        int d = atomicAdd(done, 1);
        s_last = (d == (int)(gridDim.x * gridDim.y) - 1);
    }
    __syncthreads();
    if (!s_last) return;
    __threadfence();   // acquire all blocks' writes

    const int ntask = n * 3;
    float L = 0.f, S = 0.f;
    for (int i = t; i < ntask; i += 256) {
        L += pairL1[i];
        S += pairSS[i];
    }
#pragma unroll
    for (int off = 32; off > 0; off >>= 1) {
        L += __shfl_down(L, off);
        S += __shfl_down(S, off);
    }
    if (lane == 0) { rl[wave] = L; rs[wave] = S; }
    __syncthreads();
    if (t == 0) {
        float cnt = (float)n;
        float Lt = (rl[0] + rl[1] + rl[2] + rl[3]) * (1.0f / (255.0f * (float)NPIX));
        float St = (rs[0] + rs[1] + rs[2] + rs[3]) * (1.0f / (float)NPIX);
        float m = fmaxf(cnt, 1.f);
        float loss = Lt / m + 1.f - St / m;
        out[0] = (cnt > 0.f) ? loss : 0.f;
    }
}

extern "C" void kernel_launch(void* const* d_in, const int* in_sizes, int n_in,
                              void* d_out, int out_size, void* d_ws, size_t ws_size,
                              hipStream_t stream) {
    const float* imgs = (const float*)d_in[0];  // (4,3,640,640)
    const float* gt = (const float*)d_in[1];    // (4,16,4)
    const float* pr = (const float*)d_in[2];    // (4,64,4)

    float* ws = (float*)d_ws;
    float* crops = ws;                                   // 320*3072
    float* mus = crops + (size_t)NCROP * NPIX;
    float* sigs = mus + (size_t)NCROP * NPIX;
    float* pairL1 = sigs + (size_t)NCROP * NPIX;         // 4096*3
    float* pairSS = pairL1 + (size_t)NPAIR * 3;          // 4096*3
    int* list = (int*)(pairSS + (size_t)NPAIR * 3);      // 4096
    int* count = list + NPAIR;                           // 1
    int* done = count + 1;                               // 1

    hipMemsetAsync(count, 0, 2 * sizeof(int), stream);   // count + done
    k_crop_valid<<<3 * NCROP + NPAIR / 256, 256, 0, stream>>>(imgs, gt, pr, crops, mus, sigs,
                                                             list, count);
    k_pair<<<dim3(3, NSLOT), 256, 0, stream>>>(list, count, crops, mus, sigs,
                                               pairL1, pairSS, done, (float*)d_out);
}

// Round 6
// 107.508 us; speedup vs baseline: 1.8578x; 1.8578x over previous
//
#include <hip/hip_runtime.h>
#include <math.h>

#define WIN 11
#define HALF 5
#define SZ 32
#define PST 33          /* padded LDS row stride */
#define BB 4
#define NG 16
#define NP 64
#define IH 640
#define IW 640
#define CPIX 1024       /* 32*32 per channel */
#define NPIX 3072       /* 3*32*32 per crop */
#define NCROP 320       /* 64 gt + 256 pred */
#define NPAIR 4096      /* 4*16*64 */
#define NSLOT 512       /* k_pair y-blocks per channel; grid-stride covers count>NSLOT */
#define SSIM_C1 6.5025f
#define SSIM_C2 58.5225f

// exp(-(i-5)^2/4.5)/sum — 11-tap Gaussian, sigma=1.5, compile-time
#define GW_INIT {0.001028379f, 0.007598757f, 0.036000791f, 0.109360748f, \
                 0.213005174f, 0.266011868f, 0.213005174f, 0.109360748f, \
                 0.036000791f, 0.007598757f, 0.001028379f}

// ---- fused: crop-resize + mu/sigma (blocks 0..959) | validity list (blocks 960..975) ----
// NOTE: no __threadfence anywhere — device-scope fences flush per-XCD L2 on gfx950 (r5: +100 µs).
__global__ __launch_bounds__(256) void k_crop_valid(const float* __restrict__ imgs,
                                                    const float* __restrict__ gt,
                                                    const float* __restrict__ pr,
                                                    float* __restrict__ crops,
                                                    float* __restrict__ mus,
                                                    float* __restrict__ sigs,
                                                    int* __restrict__ list,
                                                    int* __restrict__ count) {
    const int blk = blockIdx.x;
    const int t = threadIdx.x;

    if (blk >= 3 * NCROP) {
        // ---- validity -> compact list (16 blocks x 256 = 4096 pairs) ----
        int idx = (blk - 3 * NCROP) * 256 + t;
        int b = idx >> 10;
        int r = idx & 1023;
        int gi = r >> 6, pi = r & 63;
        const float* g = gt + (b * NG + gi) * 4;
        const float* p = pr + (b * NP + pi) * 4;
        float gx = g[0], gy = g[1], gw = g[2], gh = g[3];
        float px = p[0], py = p[1], pw = p[2], ph = p[3];
        float tlx = fmaxf(gx - gw * 0.5f, px - pw * 0.5f);
        float tly = fmaxf(gy - gh * 0.5f, py - ph * 0.5f);
        float brx = fminf(gx + gw * 0.5f, px + pw * 0.5f);
        float bry = fminf(gy + gh * 0.5f, py + ph * 0.5f);
        float en = ((tlx < brx) && (tly < bry)) ? 1.f : 0.f;
        float ai = (brx - tlx) * (bry - tly) * en;
        float iou = ai / (gw * gh + pw * ph - ai + 1e-16f);
        if (iou > 0.3f && pw > 2.f && ph > 2.f) {
            int s = atomicAdd(count, 1);   // wave-coalesced (G12); no fence needed
            list[s] = idx;
        }
        return;
    }

    // ---- crop path ----
    const int crop = blk / 3;
    const int c = blk - crop * 3;
    int b;
    const float* box;
    if (crop < BB * NG) {
        b = crop >> 4;
        box = gt + crop * 4;
    } else {
        int id = crop - BB * NG;
        b = id >> 6;
        box = pr + id * 4;
    }

    __shared__ float s_fx[SZ], s_fy[SZ];
    __shared__ int s_ix0[SZ], s_ix1[SZ], s_iy0[SZ], s_iy1[SZ];
    __shared__ float cr[SZ][PST];
    __shared__ float t1[SZ][PST];
    __shared__ float t2[SZ][PST];

    if (t < SZ) {
        float cx = box[0], cy = box[1], bw = box[2], bh = box[3];
        float x0 = fminf(fmaxf(floorf(cx - bw * 0.5f), 0.f), (float)(IW - 1));
        float x1 = fminf(fmaxf(floorf(cx + bw * 0.5f), 0.f), (float)IW);
        float y0 = fminf(fmaxf(floorf(cy - bh * 0.5f), 0.f), (float)(IH - 1));
        float y1 = fminf(fmaxf(floorf(cy + bh * 0.5f), 0.f), (float)IH);
        float wp = fmaxf(x1 - x0, 1.f);
        float hp = fmaxf(y1 - y0, 1.f);
        float d = (float)t + 0.5f;
        float sx = x0 + fminf(fmaxf(d * wp * (1.f / 32.f) - 0.5f, 0.f), wp - 1.f);
        float flx = floorf(sx);
        s_ix0[t] = (int)flx;
        s_fx[t] = sx - flx;
        s_ix1[t] = min((int)flx + 1, (int)(x0 + wp - 1.f));
        float sy = y0 + fminf(fmaxf(d * hp * (1.f / 32.f) - 0.5f, 0.f), hp - 1.f);
        float fly = floorf(sy);
        s_iy0[t] = (int)fly;
        s_fy[t] = sy - fly;
        s_iy1[t] = min((int)fly + 1, (int)(y0 + hp - 1.f));
    }
    __syncthreads();

    const float* ic = imgs + ((size_t)b * 3 + c) * IH * IW;
    const int y = t >> 3;          // thread owns pixels 4t..4t+3 (same row)
    const int xb = (t & 7) * 4;
    const float fy = s_fy[y];
    const float* r0 = ic + s_iy0[y] * IW;
    const float* r1 = ic + s_iy1[y] * IW;
    float vv[4];
#pragma unroll
    for (int j = 0; j < 4; ++j) {
        int x = xb + j;
        int ix0 = s_ix0[x], ix1 = s_ix1[x];
        float fx = s_fx[x];
        float v00 = r0[ix0], v01 = r0[ix1], v10 = r1[ix0], v11 = r1[ix1];
        float v = v00 * (1.f - fy) * (1.f - fx) + v01 * (1.f - fy) * fx +
                  v10 * fy * (1.f - fx) + v11 * fy * fx;
        vv[j] = v;
        cr[y][x] = v;
    }
    float* dst = crops + (size_t)crop * NPIX + c * CPIX + t * 4;
    *(float4*)dst = make_float4(vv[0], vv[1], vv[2], vv[3]);
    __syncthreads();

    constexpr float GW[WIN] = GW_INIT;
    // horizontal pass on x and x^2
#pragma unroll
    for (int j = 0; j < 4; ++j) {
        int x = xb + j;
        float a1 = 0.f, a2 = 0.f;
#pragma unroll
        for (int k = 0; k < WIN; ++k) {
            int xx = x + k - HALF;
            if (xx >= 0 && xx < SZ) {
                float v = cr[y][xx];
                a1 += GW[k] * v;
                a2 += GW[k] * v * v;
            }
        }
        t1[y][x] = a1;
        t2[y][x] = a2;
    }
    __syncthreads();
    // vertical pass
    float m[4], s[4];
#pragma unroll
    for (int j = 0; j < 4; ++j) {
        int x = xb + j;
        float a1 = 0.f, a2 = 0.f;
#pragma unroll
        for (int k = 0; k < WIN; ++k) {
            int yy = y + k - HALF;
            if (yy >= 0 && yy < SZ) {
                a1 += GW[k] * t1[yy][x];
                a2 += GW[k] * t2[yy][x];
            }
        }
        m[j] = a1;
        s[j] = a2 - a1 * a1;
    }
    float* mdst = mus + (size_t)crop * NPIX + c * CPIX + t * 4;
    float* sdst = sigs + (size_t)crop * NPIX + c * CPIX + t * 4;
    *(float4*)mdst = make_float4(m[0], m[1], m[2], m[3]);
    *(float4*)sdst = make_float4(s[0], s[1], s[2], s[3]);
}

// ---- per-(valid-pair, channel) SSIM + L1 via compact list; block sums via device atomics ----
__global__ __launch_bounds__(256) void k_pair(const int* __restrict__ list,
                                              const int* __restrict__ count,
                                              const float* __restrict__ crops,
                                              const float* __restrict__ mus,
                                              const float* __restrict__ sigs,
                                              float* __restrict__ acc) {
    const int c = blockIdx.x;      // 0..2
    const int n = *count;
    const int t = threadIdx.x;
    const int y = t >> 3;
    const int xb = (t & 7) * 4;
    const int wave = t >> 6, lane = t & 63;

    __shared__ float gp[SZ][PST];
    __shared__ float tmp[SZ][PST];
    __shared__ float rl[4], rs[4];
    constexpr float GW[WIN] = GW_INIT;

    for (int slot = blockIdx.y; slot < n; slot += NSLOT) {
        const int pair = list[slot];
        const int b = pair >> 10;
        const int r = pair & 1023;
        const int gi = r >> 6, pi = r & 63;
        const size_t goff = (size_t)(b * NG + gi) * NPIX + c * CPIX;
        const size_t poff = (size_t)(BB * NG + b * NP + pi) * NPIX + c * CPIX;

        float4 gv = *(const float4*)(crops + goff + t * 4);
        float4 pv = *(const float4*)(crops + poff + t * 4);
        // hoist mu/sigma loads: in flight across both conv phases
        float4 mg = *(const float4*)(mus + goff + t * 4);
        float4 mp = *(const float4*)(mus + poff + t * 4);
        float4 sg = *(const float4*)(sigs + goff + t * 4);
        float4 sp = *(const float4*)(sigs + poff + t * 4);

        float l1 = fabsf(gv.x - pv.x) + fabsf(gv.y - pv.y) +
                   fabsf(gv.z - pv.z) + fabsf(gv.w - pv.w);
        gp[y][xb + 0] = gv.x * pv.x;
        gp[y][xb + 1] = gv.y * pv.y;
        gp[y][xb + 2] = gv.z * pv.z;
        gp[y][xb + 3] = gv.w * pv.w;
        __syncthreads();

#pragma unroll
        for (int j = 0; j < 4; ++j) {
            int x = xb + j;
            float a = 0.f;
#pragma unroll
            for (int k = 0; k < WIN; ++k) {
                int xx = x + k - HALF;
                if (xx >= 0 && xx < SZ) a += GW[k] * gp[y][xx];
            }
            tmp[y][x] = a;
        }
        __syncthreads();

        float mgv[4] = {mg.x, mg.y, mg.z, mg.w};
        float mpv[4] = {mp.x, mp.y, mp.z, mp.w};
        float sgv[4] = {sg.x, sg.y, sg.z, sg.w};
        float spv[4] = {sp.x, sp.y, sp.z, sp.w};
        float ss = 0.f;
#pragma unroll
        for (int j = 0; j < 4; ++j) {
            int x = xb + j;
            float a = 0.f;
#pragma unroll
            for (int k = 0; k < WIN; ++k) {
                int yy = y + k - HALF;
                if (yy >= 0 && yy < SZ) a += GW[k] * tmp[yy][x];
            }
            float m1 = mgv[j], m2 = mpv[j];
            float sgp = a - m1 * m2;
            float num = (2.f * m1 * m2 + SSIM_C1) * (2.f * sgp + SSIM_C2);
            float den = (m1 * m1 + m2 * m2 + SSIM_C1) * (sgv[j] + spv[j] + SSIM_C2);
            ss += num / den;
        }

        // block reduction: 64-lane shuffle, then LDS across 4 waves
#pragma unroll
        for (int off = 32; off > 0; off >>= 1) {
            l1 += __shfl_down(l1, off);
            ss += __shfl_down(ss, off);
        }
        if (lane == 0) { rl[wave] = l1; rs[wave] = ss; }
        __syncthreads();
        if (t == 0) {
            // device-scope fp atomics: fast HW path, no L2 flush (unlike __threadfence)
            atomicAdd(&acc[0], rl[0] + rl[1] + rl[2] + rl[3]);
            atomicAdd(&acc[1], rs[0] + rs[1] + rs[2] + rs[3]);
        }
        __syncthreads();   // protect rl/rs reuse across grid-stride iterations
    }
}

// ---- finalize: tiny kernel, reads 3 scalars ----
__global__ void k_final(const int* __restrict__ count,
                        const float* __restrict__ acc,
                        float* __restrict__ out) {
    float cnt = (float)(*count);
    float Lt = acc[0] * (1.0f / (255.0f * (float)NPIX));
    float St = acc[1] * (1.0f / (float)NPIX);
    float m = fmaxf(cnt, 1.f);
    float loss = Lt / m + 1.f - St / m;
    out[0] = (cnt > 0.f) ? loss : 0.f;
}

extern "C" void kernel_launch(void* const* d_in, const int* in_sizes, int n_in,
                              void* d_out, int out_size, void* d_ws, size_t ws_size,
                              hipStream_t stream) {
    const float* imgs = (const float*)d_in[0];  // (4,3,640,640)
    const float* gt = (const float*)d_in[1];    // (4,16,4)
    const float* pr = (const float*)d_in[2];    // (4,64,4)

    float* ws = (float*)d_ws;
    float* crops = ws;                                   // 320*3072
    float* mus = crops + (size_t)NCROP * NPIX;
    float* sigs = mus + (size_t)NCROP * NPIX;
    float* acc = sigs + (size_t)NCROP * NPIX;            // 2 floats: L1 sum, SSIM sum
    int* count = (int*)(acc + 2);                        // 1 int
    int* list = count + 1;                               // 4096

    hipMemsetAsync(acc, 0, 3 * sizeof(float), stream);   // acc[0], acc[1], count
    k_crop_valid<<<3 * NCROP + NPAIR / 256, 256, 0, stream>>>(imgs, gt, pr, crops, mus, sigs,
                                                             list, count);
    k_pair<<<dim3(3, NSLOT), 256, 0, stream>>>(list, count, crops, mus, sigs, acc);
    k_final<<<1, 1, 0, stream>>>(count, acc, (float*)d_out);
}

// Round 7
// 88.455 us; speedup vs baseline: 2.2580x; 1.2154x over previous
//
#include <hip/hip_runtime.h>
#include <math.h>

#define WIN 11
#define HALF 5
#define SZ 32
#define PST 33          /* padded LDS row stride */
#define BB 4
#define NG 16
#define NP 64
#define IH 640
#define IW 640
#define CPIX 1024       /* 32*32 per channel */
#define NPIX 3072       /* 3*32*32 per crop */
#define NCROP 320       /* 64 gt + 256 pred */
#define NPAIR 4096      /* 4*16*64 */
#define NSLOT 512       /* k_pair y-blocks per channel; grid-stride covers count>NSLOT */
#define SSIM_C1 6.5025f
#define SSIM_C2 58.5225f

// exp(-(i-5)^2/4.5)/sum — 11-tap Gaussian, sigma=1.5, compile-time
#define GW_INIT {0.001028379f, 0.007598757f, 0.036000791f, 0.109360748f, \
                 0.213005174f, 0.266011868f, 0.213005174f, 0.109360748f, \
                 0.036000791f, 0.007598757f, 0.001028379f}

// Lessons encoded here:
//  - NO __threadfence (r5: device fence flushes per-XCD L2, +100 µs).
//  - NO contended fp atomicAdd for result accumulation (r2/r6 vs r3: +16 µs);
//    store to unique cells + tiny reduce kernel instead.
//  - NO memset dispatch: single-block ballot compaction writes count/list with
//    plain stores; nothing reads uninitialized (0xAA-poisoned) workspace.

// ---- fused: crop-resize + mu/sigma (blocks 0..959) | validity compaction (block 960) ----
__global__ __launch_bounds__(256) void k_crop_valid(const float* __restrict__ imgs,
                                                    const float* __restrict__ gt,
                                                    const float* __restrict__ pr,
                                                    float* __restrict__ crops,
                                                    float* __restrict__ mus,
                                                    float* __restrict__ sigs,
                                                    int* __restrict__ list,
                                                    int* __restrict__ count) {
    const int blk = blockIdx.x;
    const int t = threadIdx.x;

    if (blk == 3 * NCROP) {
        // ---- validity -> compact list, single block, no atomics ----
        __shared__ int s_wcnt[4];
        __shared__ int s_base;
        const int wave = t >> 6, lane = t & 63;
        if (t == 0) s_base = 0;
#pragma unroll 1
        for (int iter = 0; iter < NPAIR / 256; ++iter) {
            int idx = iter * 256 + t;
            int b = idx >> 10;
            int r = idx & 1023;
            int gi = r >> 6, pi = r & 63;
            const float* g = gt + (b * NG + gi) * 4;
            const float* p = pr + (b * NP + pi) * 4;
            float gx = g[0], gy = g[1], gw = g[2], gh = g[3];
            float px = p[0], py = p[1], pw = p[2], ph = p[3];
            float tlx = fmaxf(gx - gw * 0.5f, px - pw * 0.5f);
            float tly = fmaxf(gy - gh * 0.5f, py - ph * 0.5f);
            float brx = fminf(gx + gw * 0.5f, px + pw * 0.5f);
            float bry = fminf(gy + gh * 0.5f, py + ph * 0.5f);
            float en = ((tlx < brx) && (tly < bry)) ? 1.f : 0.f;
            float ai = (brx - tlx) * (bry - tly) * en;
            float iou = ai / (gw * gh + pw * ph - ai + 1e-16f);
            bool valid = (iou > 0.3f && pw > 2.f && ph > 2.f);
            unsigned long long m = __ballot(valid);
            if (lane == 0) s_wcnt[wave] = __popcll(m);
            __syncthreads();   // A: counts + prev-iter s_base stable
            int base = s_base;
            int woff = base;
#pragma unroll
            for (int w = 0; w < 4; ++w)
                if (w < wave) woff += s_wcnt[w];
            int sum = s_wcnt[0] + s_wcnt[1] + s_wcnt[2] + s_wcnt[3];
            if (valid) {
                int pos = woff + __popcll(m & ((1ull << lane) - 1ull));
                list[pos] = idx;
            }
            __syncthreads();   // B: all reads of s_base/s_wcnt done
            if (t == 0) s_base = base + sum;
        }
        __syncthreads();
        if (t == 0) *count = s_base;
        return;
    }

    // ---- crop path: per-thread bilinear indices (no index-stage barrier) ----
    const int crop = blk / 3;
    const int c = blk - crop * 3;
    int b;
    const float* box;
    if (crop < BB * NG) {
        b = crop >> 4;
        box = gt + crop * 4;
    } else {
        int id = crop - BB * NG;
        b = id >> 6;
        box = pr + id * 4;
    }

    __shared__ float cr[SZ][PST];
    __shared__ float t1[SZ][PST];
    __shared__ float t2[SZ][PST];

    // box is wave-uniform -> scalar loads
    float cx = box[0], cy = box[1], bw = box[2], bh = box[3];
    float x0 = fminf(fmaxf(floorf(cx - bw * 0.5f), 0.f), (float)(IW - 1));
    float x1 = fminf(fmaxf(floorf(cx + bw * 0.5f), 0.f), (float)IW);
    float y0 = fminf(fmaxf(floorf(cy - bh * 0.5f), 0.f), (float)(IH - 1));
    float y1 = fminf(fmaxf(floorf(cy + bh * 0.5f), 0.f), (float)IH);
    float wp = fmaxf(x1 - x0, 1.f);
    float hp = fmaxf(y1 - y0, 1.f);
    int xmax = (int)(x0 + wp - 1.f);
    int ymax = (int)(y0 + hp - 1.f);

    const int y = t >> 3;          // thread owns pixels (y, xb..xb+3)
    const int xb = (t & 7) * 4;

    float sy = y0 + fminf(fmaxf(((float)y + 0.5f) * hp * (1.f / 32.f) - 0.5f, 0.f), hp - 1.f);
    float fly = floorf(sy);
    int iy0 = (int)fly;
    float fy = sy - fly;
    int iy1 = min(iy0 + 1, ymax);

    const float* ic = imgs + ((size_t)b * 3 + c) * IH * IW;
    const float* r0 = ic + iy0 * IW;
    const float* r1 = ic + iy1 * IW;
    float vv[4];
#pragma unroll
    for (int j = 0; j < 4; ++j) {
        int x = xb + j;
        float sx = x0 + fminf(fmaxf(((float)x + 0.5f) * wp * (1.f / 32.f) - 0.5f, 0.f), wp - 1.f);
        float flx = floorf(sx);
        int ix0 = (int)flx;
        float fx = sx - flx;
        int ix1 = min(ix0 + 1, xmax);
        float v00 = r0[ix0], v01 = r0[ix1], v10 = r1[ix0], v11 = r1[ix1];
        float v = v00 * (1.f - fy) * (1.f - fx) + v01 * (1.f - fy) * fx +
                  v10 * fy * (1.f - fx) + v11 * fy * fx;
        vv[j] = v;
        cr[y][x] = v;
    }
    float* dst = crops + (size_t)crop * NPIX + c * CPIX + t * 4;
    *(float4*)dst = make_float4(vv[0], vv[1], vv[2], vv[3]);
    __syncthreads();

    constexpr float GW[WIN] = GW_INIT;
    // horizontal pass on x and x^2
#pragma unroll
    for (int j = 0; j < 4; ++j) {
        int x = xb + j;
        float a1 = 0.f, a2 = 0.f;
#pragma unroll
        for (int k = 0; k < WIN; ++k) {
            int xx = x + k - HALF;
            if (xx >= 0 && xx < SZ) {
                float v = cr[y][xx];
                a1 += GW[k] * v;
                a2 += GW[k] * v * v;
            }
        }
        t1[y][x] = a1;
        t2[y][x] = a2;
    }
    __syncthreads();
    // vertical pass
    float m[4], s[4];
#pragma unroll
    for (int j = 0; j < 4; ++j) {
        int x = xb + j;
        float a1 = 0.f, a2 = 0.f;
#pragma unroll
        for (int k = 0; k < WIN; ++k) {
            int yy = y + k - HALF;
            if (yy >= 0 && yy < SZ) {
                a1 += GW[k] * t1[yy][x];
                a2 += GW[k] * t2[yy][x];
            }
        }
        m[j] = a1;
        s[j] = a2 - a1 * a1;
    }
    float* mdst = mus + (size_t)crop * NPIX + c * CPIX + t * 4;
    float* sdst = sigs + (size_t)crop * NPIX + c * CPIX + t * 4;
    *(float4*)mdst = make_float4(m[0], m[1], m[2], m[3]);
    *(float4*)sdst = make_float4(s[0], s[1], s[2], s[3]);
}

// ---- per-(valid-pair, channel) SSIM + L1; unique-cell stores (r3-measured-fast) ----
__global__ __launch_bounds__(256) void k_pair(const int* __restrict__ list,
                                              const int* __restrict__ count,
                                              const float* __restrict__ crops,
                                              const float* __restrict__ mus,
                                              const float* __restrict__ sigs,
                                              float* __restrict__ pairL1,
                                              float* __restrict__ pairSS) {
    const int c = blockIdx.x;      // 0..2
    const int n = *count;
    const int t = threadIdx.x;
    const int y = t >> 3;
    const int xb = (t & 7) * 4;
    const int wave = t >> 6, lane = t & 63;

    __shared__ float gp[SZ][PST];
    __shared__ float tmp[SZ][PST];
    __shared__ float rl[4], rs[4];
    constexpr float GW[WIN] = GW_INIT;

    for (int slot = blockIdx.y; slot < n; slot += NSLOT) {
        const int pair = list[slot];
        const int b = pair >> 10;
        const int r = pair & 1023;
        const int gi = r >> 6, pi = r & 63;
        const size_t goff = (size_t)(b * NG + gi) * NPIX + c * CPIX;
        const size_t poff = (size_t)(BB * NG + b * NP + pi) * NPIX + c * CPIX;

        float4 gv = *(const float4*)(crops + goff + t * 4);
        float4 pv = *(const float4*)(crops + poff + t * 4);
        // hoist mu/sigma loads: in flight across both conv phases
        float4 mg = *(const float4*)(mus + goff + t * 4);
        float4 mp = *(const float4*)(mus + poff + t * 4);
        float4 sg = *(const float4*)(sigs + goff + t * 4);
        float4 sp = *(const float4*)(sigs + poff + t * 4);

        float l1 = fabsf(gv.x - pv.x) + fabsf(gv.y - pv.y) +
                   fabsf(gv.z - pv.z) + fabsf(gv.w - pv.w);
        gp[y][xb + 0] = gv.x * pv.x;
        gp[y][xb + 1] = gv.y * pv.y;
        gp[y][xb + 2] = gv.z * pv.z;
        gp[y][xb + 3] = gv.w * pv.w;
        __syncthreads();

#pragma unroll
        for (int j = 0; j < 4; ++j) {
            int x = xb + j;
            float a = 0.f;
#pragma unroll
            for (int k = 0; k < WIN; ++k) {
                int xx = x + k - HALF;
                if (xx >= 0 && xx < SZ) a += GW[k] * gp[y][xx];
            }
            tmp[y][x] = a;
        }
        __syncthreads();

        float mgv[4] = {mg.x, mg.y, mg.z, mg.w};
        float mpv[4] = {mp.x, mp.y, mp.z, mp.w};
        float sgv[4] = {sg.x, sg.y, sg.z, sg.w};
        float spv[4] = {sp.x, sp.y, sp.z, sp.w};
        float ss = 0.f;
#pragma unroll
        for (int j = 0; j < 4; ++j) {
            int x = xb + j;
            float a = 0.f;
#pragma unroll
            for (int k = 0; k < WIN; ++k) {
                int yy = y + k - HALF;
                if (yy >= 0 && yy < SZ) a += GW[k] * tmp[yy][x];
            }
            float m1 = mgv[j], m2 = mpv[j];
            float sgp = a - m1 * m2;
            float num = (2.f * m1 * m2 + SSIM_C1) * (2.f * sgp + SSIM_C2);
            float den = (m1 * m1 + m2 * m2 + SSIM_C1) * (sgv[j] + spv[j] + SSIM_C2);
            ss += num / den;
        }

        // block reduction: 64-lane shuffle, then LDS across 4 waves
#pragma unroll
        for (int off = 32; off > 0; off >>= 1) {
            l1 += __shfl_down(l1, off);
            ss += __shfl_down(ss, off);
        }
        if (lane == 0) { rl[wave] = l1; rs[wave] = ss; }
        __syncthreads();
        if (t == 0) {
            pairL1[slot * 3 + c] = rl[0] + rl[1] + rl[2] + rl[3];
            pairSS[slot * 3 + c] = rs[0] + rs[1] + rs[2] + rs[3];
        }
    }
}

// ---- finalize: deterministic reduction over compact results ----
__global__ __launch_bounds__(256) void k_final(const int* __restrict__ count,
                                               const float* __restrict__ pairL1,
                                               const float* __restrict__ pairSS,
                                               float* __restrict__ out) {
    const int n3 = (*count) * 3;
    const int t = threadIdx.x;
    float L = 0.f, S = 0.f;
    for (int i = t; i < n3; i += 256) {
        L += pairL1[i];
        S += pairSS[i];
    }
    __shared__ float rl[4], rs[4];
#pragma unroll
    for (int off = 32; off > 0; off >>= 1) {
        L += __shfl_down(L, off);
        S += __shfl_down(S, off);
    }
    const int wave = t >> 6, lane = t & 63;
    if (lane == 0) { rl[wave] = L; rs[wave] = S; }
    __syncthreads();
    if (t == 0) {
        float cnt = (float)(*count);
        float Lt = (rl[0] + rl[1] + rl[2] + rl[3]) * (1.0f / (255.0f * (float)NPIX));
        float St = (rs[0] + rs[1] + rs[2] + rs[3]) * (1.0f / (float)NPIX);
        float m = fmaxf(cnt, 1.f);
        float loss = Lt / m + 1.f - St / m;
        out[0] = (cnt > 0.f) ? loss : 0.f;
    }
}

extern "C" void kernel_launch(void* const* d_in, const int* in_sizes, int n_in,
                              void* d_out, int out_size, void* d_ws, size_t ws_size,
                              hipStream_t stream) {
    const float* imgs = (const float*)d_in[0];  // (4,3,640,640)
    const float* gt = (const float*)d_in[1];    // (4,16,4)
    const float* pr = (const float*)d_in[2];    // (4,64,4)

    float* ws = (float*)d_ws;
    float* crops = ws;                                   // 320*3072
    float* mus = crops + (size_t)NCROP * NPIX;
    float* sigs = mus + (size_t)NCROP * NPIX;
    float* pairL1 = sigs + (size_t)NCROP * NPIX;         // 4096*3
    float* pairSS = pairL1 + (size_t)NPAIR * 3;          // 4096*3
    int* list = (int*)(pairSS + (size_t)NPAIR * 3);      // 4096
    int* count = list + NPAIR;                           // 1

    k_crop_valid<<<3 * NCROP + 1, 256, 0, stream>>>(imgs, gt, pr, crops, mus, sigs,
                                                    list, count);
    k_pair<<<dim3(3, NSLOT), 256, 0, stream>>>(list, count, crops, mus, sigs,
                                               pairL1, pairSS);
    k_final<<<1, 256, 0, stream>>>(count, pairL1, pairSS, (float*)d_out);
}